// Round 3
// baseline (197.911 us; speedup 1.0000x reference)
//
#include <hip/hip_runtime.h>

// dense_image_warp R10: direct cached gather -- no LDS, no barriers.
//
// R9 post-mortem: occupancy 52->70% and bank-geometry change moved NOTHING
// (60.5 -> 60.2 us, conflicts unchanged). Two different stage->barrier->
// LDS-gather kernels hit an identical 60 us wall with every pipe <30% busy.
// The shared structure is the limiter: staging moves 233 MB (3x halo
// over-read) global->LDS, gathers pull 302 MB back out with conflicts, in
// barrier-separated phases -- while the whole dataset (221 MB) is
// L3-resident and flow is only +-5 px, so gathers have extreme line reuse.
// R10 deletes the staging: every pixel does the (already-verified) direct
// global bilinear path. 2D tiles + XCD swizzle keep L1/L2 locality;
// 2 independent px/thread for ILP; 32 waves/CU, zero sync points.
// Roofline here: HBM 138 MB -> 22 us, L2 ~300 MB -> 9 us, VALU ~7 us.

constexpr int B = 8;
constexpr int H = 1024;
constexpr int W = 768;
constexpr int C = 3;

constexpr int TY = 32, TX = 32;          // tile = one block
constexpr int TILES_X = W / TX;          // 24
constexpr int TILES_Y = H / TY;          // 32
constexpr int TILES_PER_B = TILES_X * TILES_Y;   // 768

constexpr int NTHREADS = 512;            // 8 waves/block
constexpr int PX_PER_T = (TY * TX) / NTHREADS;   // 2

typedef float vfloat2 __attribute__((ext_vector_type(2)));
typedef float vfloat4 __attribute__((ext_vector_type(4)));
typedef float vfloat2_a4 __attribute__((ext_vector_type(2), aligned(4)));
typedef float vfloat4_a4 __attribute__((ext_vector_type(4), aligned(4)));

__global__ __launch_bounds__(NTHREADS, 8) void warp_kernel(
    const float* __restrict__ image,   // [B,H,W,3]
    const float* __restrict__ flow,    // [B,H,W,2]
    float* __restrict__ out)           // [B,H,W,3]
{
    // ---- XCD-aware decomposition: blockIdx%8 = XCD = batch ----
    const int flat = blockIdx.x;            // 0..6143
    const int b    = flat & 7;
    const int s    = flat >> 3;             // temporal order within XCD
    const int ty   = s / TILES_X;
    const int tx   = s - ty * TILES_X;
    const int Y0 = ty * TY, X0 = tx * TX;

    const float* imgB = image + (size_t)b * H * (W * C);

    // ---- phase 1: flow loads (streaming, no reuse) ----
    int yy[PX_PER_T], xx[PX_PER_T];
    vfloat2 f[PX_PER_T];
#pragma unroll
    for (int k = 0; k < PX_PER_T; ++k) {
        const int p = threadIdx.x + k * NTHREADS;
        yy[k] = Y0 + (p >> 5);
        xx[k] = X0 + (p & 31);
        f[k] = __builtin_nontemporal_load(
            (const vfloat2*)flow + (((size_t)b * H + yy[k]) * W + xx[k]));
    }

    // ---- phase 2: addresses + issue all 8 tap loads (2 px x 4) ----
    // Independent chains; compiler schedules waitcnts. Taps hit L1/L2:
    // flow sigma=5px so neighboring lanes/waves reuse the same 64B lines.
    vfloat4 t4[PX_PER_T], b4[PX_PER_T];
    vfloat2 t2[PX_PER_T], b2[PX_PER_T];
    float ax[PX_PER_T], ay[PX_PER_T];
#pragma unroll
    for (int k = 0; k < PX_PER_T; ++k) {
        const float qy = (float)yy[k] - f[k].x;
        const float qx = (float)xx[k] - f[k].y;
        float y0f = floorf(qy);
        float x0f = floorf(qx);
        y0f = fminf(fmaxf(y0f, 0.0f), (float)(H - 2));
        x0f = fminf(fmaxf(x0f, 0.0f), (float)(W - 2));
        ay[k] = fminf(fmaxf(qy - y0f, 0.0f), 1.0f);
        ax[k] = fminf(fmaxf(qx - x0f, 0.0f), 1.0f);

        const float* top = imgB + ((size_t)(int)y0f * W + (int)x0f) * C;
        const float* bot = top + (size_t)W * C;
        t4[k] = *(const vfloat4_a4*)top;         // tl0..2, tr0
        t2[k] = *(const vfloat2_a4*)(top + 4);   // tr1..2
        b4[k] = *(const vfloat4_a4*)bot;         // bl0..2, br0
        b2[k] = *(const vfloat2_a4*)(bot + 4);   // br1..2
    }

    // ---- phase 3: lerp + store ----
#pragma unroll
    for (int k = 0; k < PX_PER_T; ++k) {
        const float tl0 = t4[k].x, tl1 = t4[k].y, tl2 = t4[k].z;
        const float tr0 = t4[k].w, tr1 = t2[k].x, tr2 = t2[k].y;
        const float bl0 = b4[k].x, bl1 = b4[k].y, bl2 = b4[k].z;
        const float br0 = b4[k].w, br1 = b2[k].x, br2 = b2[k].y;

        const float tp0 = tl0 + ax[k] * (tr0 - tl0);
        const float tp1 = tl1 + ax[k] * (tr1 - tl1);
        const float tp2 = tl2 + ax[k] * (tr2 - tl2);
        const float bo0 = bl0 + ax[k] * (br0 - bl0);
        const float bo1 = bl1 + ax[k] * (br1 - bl1);
        const float bo2 = bl2 + ax[k] * (br2 - bl2);

        float* o = out + (((size_t)b * H + yy[k]) * W + xx[k]) * C;
        __builtin_nontemporal_store(tp0 + ay[k] * (bo0 - tp0), &o[0]);
        __builtin_nontemporal_store(tp1 + ay[k] * (bo1 - tp1), &o[1]);
        __builtin_nontemporal_store(tp2 + ay[k] * (bo2 - tp2), &o[2]);
    }
}

extern "C" void kernel_launch(void* const* d_in, const int* in_sizes, int n_in,
                              void* d_out, int out_size, void* d_ws, size_t ws_size,
                              hipStream_t stream) {
    const float* image = (const float*)d_in[0];
    const float* flow  = (const float*)d_in[1];
    float* out = (float*)d_out;

    dim3 grid(B * TILES_PER_B);   // 6144 blocks, 24 rounds of 4/CU
    dim3 block(NTHREADS);
    warp_kernel<<<grid, block, 0, stream>>>(image, flow, out);
}

// Round 4
// 181.803 us; speedup vs baseline: 1.0886x; 1.0886x over previous
//
#include <hip/hip_runtime.h>

// dense_image_warp R11: R9 staged structure + 4 px/thread vectorized I/O.
//
// R10 post-mortem: direct VMEM gather REGRESSED (60->81us, VALU 8.5%) --
// scattered per-lane global loads serialize in TA/L1; LDS is the only unit
// serving 64 scattered lanes/instr cheaply. Staging stays. The 60us wall is
// phase-locked convoys (barrier aligns all waves: LDS burst -> VALU burst ->
// store burst; pipes used serially, each <30% avg). Most compressible term:
// VMEM instruction pressure. R11: each thread owns 4 consecutive x px ->
// output 48B = 3 aligned dwordx4 stores (was 12 scalar stride-12 dword),
// flow = 2 aligned dwordx4 (was 4 dwordx2), 24 ds_reads batched per thread
// for LDS pipelining, address math amortized 2x. Tile 64x32, 512 thr,
// window 97x64 @ 192-fl stride (R9's 196 pad = verified null, reverted),
// 76.9 KB -> 2 blocks/CU.

constexpr int B = 8;
constexpr int H = 1024;
constexpr int W = 768;
constexpr int C = 3;

constexpr int TY = 64, TX = 32;          // output tile
constexpr int WIN_ROWS = 97;             // TY + 16 up + 16 down + 1
constexpr int WIN_COLS = 64;             // TX + 16 halo each side
constexpr int WSF = WIN_COLS * C;        // 192 floats = 768 B per row
constexpr int ROW_CHUNKS = WSF / 4;      // 48 x 16B chunks per row
constexpr int CHUNKS = WIN_ROWS * ROW_CHUNKS;    // 4656
constexpr int TILES_X = W / TX;          // 24
constexpr int TILES_Y = H / TY;          // 16
constexpr int TILES_PER_B = TILES_X * TILES_Y;   // 384

constexpr int NTHREADS = 512;            // 8 waves/block
constexpr int NWAVES = NTHREADS / 64;
constexpr int PXX = 4;                   // consecutive x px per thread

typedef float vfloat2 __attribute__((ext_vector_type(2)));
typedef float vfloat4 __attribute__((ext_vector_type(4)));
typedef float vfloat2_a4 __attribute__((ext_vector_type(2), aligned(4)));
typedef float vfloat4_a4 __attribute__((ext_vector_type(4), aligned(4)));

__global__ __launch_bounds__(NTHREADS, 4) void warp_kernel(
    const float* __restrict__ image,   // [B,H,W,3]
    const float* __restrict__ flow,    // [B,H,W,2]
    float* __restrict__ out)           // [B,H,W,3]
{
    // +64 floats: clamped tail lanes of last staging issue land here
    __shared__ float win[WIN_ROWS * WSF + 64];   // 76912 B -> 2 blocks/CU

    // ---- XCD-aware decomposition: blockIdx%8 = XCD = batch ----
    const int flat = blockIdx.x;            // 0..3071
    const int b    = flat & 7;
    const int s    = flat >> 3;             // temporal order within XCD
    const int ty   = s / TILES_X;
    const int tx   = s - ty * TILES_X;
    const int Y0 = ty * TY, X0 = tx * TX;

    const int rowLo = min(max(Y0 - 16, 0), H - WIN_ROWS);
    const int colLo = min(max(X0 - 16, 0), W - WIN_COLS);   // mult of 16

    const int lane = threadIdx.x & 63;
    const int wv   = threadIdx.x >> 6;      // 0..7

    // ---- async staging: issue all global_load_lds, no intervening waits ----
    const float* gwin = image + ((size_t)b * H + rowLo) * (W * C) + colLo * C;
#pragma unroll 1
    for (int j = wv; j * 64 < CHUNKS; j += NWAVES) {
        int ci = j * 64 + lane;
        if (ci >= CHUNKS) ci = CHUNKS - 1;        // tail clamp -> end padding
        const int r = ci / ROW_CHUNKS;            // magic-mul div
        const int c = ci - r * ROW_CHUNKS;
        const float* g = gwin + (size_t)r * (W * C) + c * 4;
        __builtin_amdgcn_global_load_lds(
            (const __attribute__((address_space(1))) void*)g,
            (__attribute__((address_space(3))) void*)(win + (size_t)j * 256),
            16, 0, 0);
    }

    // ---- this thread's 4-px run ----
    const int pr  = threadIdx.x >> 3;        // 0..63 row in tile
    const int xo  = (threadIdx.x & 7) * 4;   // 0,4,...,28 col offset
    const int y   = Y0 + pr;
    const int x   = X0 + xo;
    const size_t pix = ((size_t)b * H + y) * W + x;

    // ---- flow loads before barrier: latency hides under staging ----
    // 32B @ 32B-aligned: (dy0,dx0,dy1,dx1),(dy2,dx2,dy3,dx3)
    const vfloat4 fA = __builtin_nontemporal_load((const vfloat4*)(flow + pix * 2));
    const vfloat4 fB = __builtin_nontemporal_load((const vfloat4*)(flow + pix * 2) + 1);

    __syncthreads();   // drains vmcnt: staging + flow complete

    const float fy[PXX] = {fA.x, fA.z, fB.x, fB.z};
    const float fx[PXX] = {fA.y, fA.w, fB.y, fB.w};

    float res[PXX][3];
#pragma unroll
    for (int k = 0; k < PXX; ++k) {
        const float qy = (float)y       - fy[k];
        const float qx = (float)(x + k) - fx[k];

        float y0f = floorf(qy);
        float x0f = floorf(qx);
        y0f = fminf(fmaxf(y0f, 0.0f), (float)(H - 2));
        x0f = fminf(fmaxf(x0f, 0.0f), (float)(W - 2));
        const float ay = fminf(fmaxf(qy - y0f, 0.0f), 1.0f);
        const float ax = fminf(fmaxf(qx - x0f, 0.0f), 1.0f);

        const int y0 = (int)y0f;
        const int x0 = (int)x0f;

        float tl0, tl1, tl2, tr0, tr1, tr2, bl0, bl1, bl2, br0, br1, br2;

        const bool inwin = (y0 >= rowLo) & (y0 <= rowLo + WIN_ROWS - 2) &
                           (x0 >= colLo) & (x0 <= colLo + WIN_COLS - 2);
        if (inwin) {
            const float* t = &win[(y0 - rowLo) * WSF + (x0 - colLo) * C];
            tl0 = t[0]; tl1 = t[1]; tl2 = t[2];
            tr0 = t[3]; tr1 = t[4]; tr2 = t[5];
            const float* bo = t + WSF;
            bl0 = bo[0]; bl1 = bo[1]; bl2 = bo[2];
            br0 = bo[3]; br1 = bo[4]; br2 = bo[5];
        } else {
            // rare (~0.4% px): flow beyond halo -> direct global bilinear
            const float* top = image + (((size_t)b * H + y0) * W + x0) * C;
            const float* bot = top + (size_t)W * C;
            const vfloat4 t4 = *(const vfloat4_a4*)top;
            const vfloat2 t2 = *(const vfloat2_a4*)(top + 4);
            const vfloat4 b4 = *(const vfloat4_a4*)bot;
            const vfloat2 b2 = *(const vfloat2_a4*)(bot + 4);
            tl0 = t4.x; tl1 = t4.y; tl2 = t4.z;
            tr0 = t4.w; tr1 = t2.x; tr2 = t2.y;
            bl0 = b4.x; bl1 = b4.y; bl2 = b4.z;
            br0 = b4.w; br1 = b2.x; br2 = b2.y;
        }

        const float tp0 = tl0 + ax * (tr0 - tl0);
        const float tp1 = tl1 + ax * (tr1 - tl1);
        const float tp2 = tl2 + ax * (tr2 - tl2);
        const float bo0 = bl0 + ax * (br0 - bl0);
        const float bo1 = bl1 + ax * (br1 - bl1);
        const float bo2 = bl2 + ax * (br2 - bl2);

        res[k][0] = tp0 + ay * (bo0 - tp0);
        res[k][1] = tp1 + ay * (bo1 - tp1);
        res[k][2] = tp2 + ay * (bo2 - tp2);
    }

    // ---- 48B contiguous output -> 3 aligned dwordx4 stores ----
    const vfloat4 o0 = {res[0][0], res[0][1], res[0][2], res[1][0]};
    const vfloat4 o1 = {res[1][1], res[1][2], res[2][0], res[2][1]};
    const vfloat4 o2 = {res[2][2], res[3][0], res[3][1], res[3][2]};
    vfloat4* o = (vfloat4*)(out + pix * C);   // pix%4==0 -> 48B-aligned
    __builtin_nontemporal_store(o0, o + 0);
    __builtin_nontemporal_store(o1, o + 1);
    __builtin_nontemporal_store(o2, o + 2);
}

extern "C" void kernel_launch(void* const* d_in, const int* in_sizes, int n_in,
                              void* d_out, int out_size, void* d_ws, size_t ws_size,
                              hipStream_t stream) {
    const float* image = (const float*)d_in[0];
    const float* flow  = (const float*)d_in[1];
    float* out = (float*)d_out;

    dim3 grid(B * TILES_PER_B);   // 3072 blocks, 12 rounds of 2/CU
    dim3 block(NTHREADS);
    warp_kernel<<<grid, block, 0, stream>>>(image, flow, out);
}

// Round 5
// 179.530 us; speedup vs baseline: 1.1024x; 1.0127x over previous
//
#include <hip/hip_runtime.h>

// dense_image_warp R12: horizontal-walk 4-panel LDS ring, 2 blocks/CU,
// counted vmcnt (stores excluded from the wait).
//
// R7-R11 post-mortem: every bulk-staged variant = 60 us at HBM 2.25 TB/s,
// and 135 MB HBM traffic / 2.25 TB/s = exactly 60 us -> HBM-DUTY-bound:
// stage-burst -> vmcnt(0) drain -> memory-silent compute gives ~30% memory
// duty (6.3 * 0.3 = 2.2 TB/s). Occupancy-insensitive (R9: 70% occ, same 60)
// because extra waves join the same block-wide convoy. R8 (continuous issue)
// failed on 1 block/CU x 12 waves, not on the idea. R12: 512 blocks (exactly
// 2/CU, one generation), each owns a 16-row strip, walks 24 tiles of 16x32.
// LDS = 4-panel ring (panel 49x32x3 f32 = 18.8 KB, panel-major so
// global_load_lds dest is linear), 75.3 KB -> 2 blocks/CU. Per iter/wave:
// 3 panel loads + 1 flow prefetch issued, then s_waitcnt vmcnt(7) drains
// only LAST iter's 4 loads -- this iter's loads AND the 3 nontemporal
// stores stay in flight across both barriers. Memory issue is uniform in
// time -> duty up.

constexpr int B = 8;
constexpr int H = 1024;
constexpr int W = 768;
constexpr int C = 3;

constexpr int TY = 16, TX = 32;          // tile per iteration
constexpr int TILES_X = W / TX;          // 24 tiles walked per block
constexpr int STRIPS  = H / TY;          // 64 strips -> grid 8*64 = 512
constexpr int WIN_ROWS = 49;             // TY + 16 up + 16 down + 1
constexpr int ROW_CHUNKS = TX * C / 4;   // 24 x 16B chunks per panel row
constexpr int PANEL_CHUNKS = WIN_ROWS * ROW_CHUNKS;   // 1176
constexpr int SLOT_FLOATS = PANEL_CHUNKS * 4;         // 4704 (18816 B)
constexpr int LAST_BASE = PANEL_CHUNKS - 64;          // 1112: clamped issues

constexpr int NTHREADS = TY * TX;        // 512 = 8 waves
constexpr int NWAVES = NTHREADS / 64;    // 8
constexpr int IPW = 3;                   // panel issues per wave (3*8=24>=19)

typedef float vfloat2 __attribute__((ext_vector_type(2)));
typedef float vfloat4 __attribute__((ext_vector_type(4)));
typedef float vfloat2_a4 __attribute__((ext_vector_type(2), aligned(4)));
typedef float vfloat4_a4 __attribute__((ext_vector_type(4), aligned(4)));

__global__ __launch_bounds__(NTHREADS, 4) void warp_kernel(
    const float* __restrict__ image,   // [B,H,W,3]
    const float* __restrict__ flow,    // [B,H,W,2]
    float* __restrict__ out)           // [B,H,W,3]
{
    // 4 ring slots, panel-major: slot s holds image-col panel p (p&3==s) as
    // [49 rows][32 cols][3ch] contiguous -> global_load_lds dest is linear.
    __shared__ float win[4 * SLOT_FLOATS];   // 75264 B -> 2 blocks/CU

    const int b  = blockIdx.x & 7;           // XCD = batch
    const int gy = blockIdx.x >> 3;          // strip 0..63
    const int Y0 = gy * TY;
    const int rowLo = min(max(Y0 - 16, 0), H - WIN_ROWS);

    const int lane = threadIdx.x & 63;
    const int wv   = threadIdx.x >> 6;       // 0..7

    const int py  = threadIdx.x >> 5;        // 0..15 row in strip
    const int pxx = threadIdx.x & 31;        // 0..31 col in tile
    const int y   = Y0 + py;
    const float yf = (float)y;
    const size_t rowBase = ((size_t)b * H + y) * W;   // + x gives pix

    const float* gstrip = image + ((size_t)b * H + rowLo) * (W * C);

    // stage panel p (image cols [32p,32p+32), rows rowLo..rowLo+48) into
    // ring slot p&3. 24 uniform issues (3/wave); issues 19..23 re-cover the
    // last 64 chunks (identical src+dest, benign, L1-hot).
    auto stage_panel = [&](int p) {
        const int pe = min(max(p, 0), TILES_X - 1);
        const float* gp = gstrip + pe * TX * C;
        float* lp = win + (p & 3) * SLOT_FLOATS;
#pragma unroll
        for (int i = 0; i < IPW; ++i) {
            const int j   = i * NWAVES + wv;           // 0..23 wave-uniform
            const int off = (j * 64 <= LAST_BASE) ? j * 64 : LAST_BASE;
            const int ci  = off + lane;                // < 1176
            const int r   = ci / ROW_CHUNKS;           // magic-mul div
            const int c   = ci - r * ROW_CHUNKS;
            const float* g = gp + (size_t)r * (W * C) + c * 4;
            __builtin_amdgcn_global_load_lds(
                (const __attribute__((address_space(1))) void*)g,
                (__attribute__((address_space(3))) void*)(lp + off * 4),
                16, 0, 0);
        }
    };

    auto load_flow = [&](int t) -> vfloat2 {
        const int xe = min(t, TILES_X - 1) * TX + pxx;
        return __builtin_nontemporal_load(
            (const vfloat2*)flow + (rowBase + xe));
    };

    // ---- prologue: panels -1,0,1 (-1 = dummy into slot 3) + flow(0) ----
    stage_panel(-1);
    stage_panel(0);
    stage_panel(1);
    vfloat2 fcur = load_flow(0);
    asm volatile("s_waitcnt vmcnt(0)" ::: "memory");
    __builtin_amdgcn_s_barrier();
    __builtin_amdgcn_sched_barrier(0);

#pragma unroll 1
    for (int t = 0; t < TILES_X; ++t) {
        stage_panel(t + 2);                       // 3 issues -> slot (t+2)&3
        const vfloat2 fnxt = load_flow(t + 1);    // 1 issue

        // Drain only last iter's 4 loads (panel t+1 + flow t). This iter's
        // 4 loads and the previous 3 stores stay in flight across barrier.
        asm volatile("s_waitcnt vmcnt(7)" ::: "memory");
        __builtin_amdgcn_s_barrier();
        __builtin_amdgcn_sched_barrier(0);

        const int X0 = t * TX;
        const int x  = X0 + pxx;

        const float qy = yf        - fcur.x;
        const float qx = (float)x  - fcur.y;

        float y0f = floorf(qy);
        float x0f = floorf(qx);
        y0f = fminf(fmaxf(y0f, 0.0f), (float)(H - 2));
        x0f = fminf(fmaxf(x0f, 0.0f), (float)(W - 2));
        const float ay = fminf(fmaxf(qy - y0f, 0.0f), 1.0f);
        const float ax = fminf(fmaxf(qx - x0f, 0.0f), 1.0f);
        const int y0 = (int)y0f;
        const int x0 = (int)x0f;

        float tl0, tl1, tl2, tr0, tr1, tr2, bl0, bl1, bl2, br0, br1, br2;

        // resident panels: t-1,t,t+1 => x0 in [X0-16, X0+46]; rows full win.
        const bool inwin = (y0 >= rowLo) & (y0 <= rowLo + WIN_ROWS - 2) &
                           (x0 >= X0 - 16) & (x0 <= X0 + 46);
        if (inwin) {
            const int ry = y0 - rowLo;
            const int x1 = x0 + 1;
            const float* aL = win + ((x0 >> 5) & 3) * SLOT_FLOATS
                                  + ry * (TX * C) + (x0 & 31) * C;
            const float* aR = win + ((x1 >> 5) & 3) * SLOT_FLOATS
                                  + ry * (TX * C) + (x1 & 31) * C;
            tl0 = aL[0]; tl1 = aL[1]; tl2 = aL[2];
            bl0 = aL[TX * C + 0]; bl1 = aL[TX * C + 1]; bl2 = aL[TX * C + 2];
            tr0 = aR[0]; tr1 = aR[1]; tr2 = aR[2];
            br0 = aR[TX * C + 0]; br1 = aR[TX * C + 1]; br2 = aR[TX * C + 2];
        } else {
            // rare (~0.4% px): flow beyond halo -> direct global bilinear
            const float* top = image + (((size_t)b * H + y0) * W + x0) * C;
            const float* bot = top + (size_t)W * C;
            const vfloat4 t4 = *(const vfloat4_a4*)top;
            const vfloat2 t2 = *(const vfloat2_a4*)(top + 4);
            const vfloat4 b4 = *(const vfloat4_a4*)bot;
            const vfloat2 b2 = *(const vfloat2_a4*)(bot + 4);
            tl0 = t4.x; tl1 = t4.y; tl2 = t4.z;
            tr0 = t4.w; tr1 = t2.x; tr2 = t2.y;
            bl0 = b4.x; bl1 = b4.y; bl2 = b4.z;
            br0 = b4.w; br1 = b2.x; br2 = b2.y;
        }

        const float tp0 = tl0 + ax * (tr0 - tl0);
        const float tp1 = tl1 + ax * (tr1 - tl1);
        const float tp2 = tl2 + ax * (tr2 - tl2);
        const float bo0 = bl0 + ax * (br0 - bl0);
        const float bo1 = bl1 + ax * (br1 - bl1);
        const float bo2 = bl2 + ax * (br2 - bl2);

        float* o = out + (rowBase + x) * C;
        __builtin_nontemporal_store(tp0 + ay * (bo0 - tp0), &o[0]);
        __builtin_nontemporal_store(tp1 + ay * (bo1 - tp1), &o[1]);
        __builtin_nontemporal_store(tp2 + ay * (bo2 - tp2), &o[2]);

        // protect slot (t+3)&3 (= panel t-1, read above) from next iter's
        // staging until every wave finishes this tile.
        __builtin_amdgcn_s_barrier();
        __builtin_amdgcn_sched_barrier(0);
        fcur = fnxt;
    }
}

extern "C" void kernel_launch(void* const* d_in, const int* in_sizes, int n_in,
                              void* d_out, int out_size, void* d_ws, size_t ws_size,
                              hipStream_t stream) {
    const float* image = (const float*)d_in[0];
    const float* flow  = (const float*)d_in[1];
    float* out = (float*)d_out;

    dim3 grid(B * STRIPS);    // 512 blocks = exactly 2 per CU
    dim3 block(NTHREADS);     // 512 threads = 8 waves
    warp_kernel<<<grid, block, 0, stream>>>(image, flow, out);
}